// Round 18
// baseline (324.667 us; speedup 1.0000x reference)
//
#include <hip/hip_runtime.h>

typedef _Float16 f16;
typedef f16  f16x4 __attribute__((ext_vector_type(4)));
typedef f16  f16x8 __attribute__((ext_vector_type(8)));
typedef float f32x4 __attribute__((ext_vector_type(4)));

#define B_  64
#define S_  2048
#define H_  512
#define K_  1024   // 2H

__device__ __forceinline__ float fast_tanh(float x){
  float ax = fabsf(x);
  float t  = __expf(-2.0f*ax);
  float r  = (1.0f - t) / (1.0f + t);
  return x < 0.0f ? -r : r;
}

// ---- k0: fused {We repack} + {dec_proj GEMV} + {C = sum|v|} ---------------
__global__ __launch_bounds__(256) void prep_k(const float* __restrict__ We,
                                              f16* __restrict__ Bg,
                                              const float* __restrict__ dh,
                                              const float* __restrict__ Wd,
                                              float* __restrict__ dp,
                                              const float* __restrict__ vvg,
                                              float* __restrict__ vC){
  __shared__ float s_dh[512];
  if (blockIdx.x < 2048){
    int idx = blockIdx.x*256 + threadIdx.x;      // 0..524287
    int k = idx >> 9, col = idx & 511;
    Bg[((k>>3)<<12) + (col<<3) + (k&7)] = (f16)We[idx];
  } else if (blockIdx.x < 2176){
    int idx = blockIdx.x - 2048;                 // 0..127
    int b = idx >> 1, cg = idx & 1;
    int col = (cg<<8) + threadIdx.x;
    for (int i = threadIdx.x; i < 512; i += 256) s_dh[i] = dh[(b<<9) + i];
    __syncthreads();
    float a0=0.f,a1=0.f,a2=0.f,a3=0.f;
    for (int k = 0; k < 512; k += 4){
      a0 += s_dh[k+0]*Wd[(k+0)*512 + col];
      a1 += s_dh[k+1]*Wd[(k+1)*512 + col];
      a2 += s_dh[k+2]*Wd[(k+2)*512 + col];
      a3 += s_dh[k+3]*Wd[(k+3)*512 + col];
    }
    dp[(b<<9) + col] = (a0+a1)+(a2+a3);
  } else {
    int t = threadIdx.x;
    float a = fabsf(vvg[t]) + fabsf(vvg[t+256]);
    #pragma unroll
    for (int o = 32; o >= 1; o >>= 1) a += __shfl_xor(a, o);
    if ((t & 63) == 0) s_dh[t>>6] = a;
    __syncthreads();
    if (t == 0) vC[0] = s_dh[0]+s_dh[1]+s_dh[2]+s_dh[3];
  }
}

// ---- k1: fused scores + unnorm-softmax + ctx partials ----
// R18: BK=128 -> 8 barrier periods (was 32). B register-direct from L2
// (R17-proven). A LDS dbuf 2x16 KB, depth-2 register prefetch, lgkm-only
// barriers. Same ascending-k accumulation order => bit-identical scores.
__global__ __launch_bounds__(512, 2) void fused_k(
    const float* __restrict__ enc,   // [64][2048][1024] f32
    const f16*   __restrict__ Bg,    // [128][512][8] f16
    const float* __restrict__ dp,    // [64][512]
    const float* __restrict__ vvg,   // [512]
    const float* __restrict__ vC,    // [1]
    const int*   __restrict__ mask,  // [64][2048]
    float*       __restrict__ pbuf,  // [64][2048]
    float*       __restrict__ denom, // [64][32]
    float*       __restrict__ part)  // [2048][1024]
{
  __shared__ __align__(16) f16 At[2][8192];    // [kgrp16][row64^(kgrp&7)][8]
  __shared__ float s_sc[64];

  const int tid  = threadIdx.x;
  const int lane = tid & 63;
  const int wave = tid >> 6;
  const int b    = blockIdx.x >> 5;
  const int s0   = (blockIdx.x & 31) << 6;

  if (tid < 64) s_sc[tid] = 0.0f;

  // A staging: 8 threads/row, each owns a 16-k chunk (64 B contiguous)
  const int arow = tid >> 3;                   // 0..63
  const int ac   = tid & 7;                    // chunk 0..7
  const float* aG = enc + ((size_t)(b*S_ + s0 + arow) << 10) + (ac << 4);
  const int kg0   = ac << 1;                   // local kgrp pair 2c, 2c+1
  const int aDst0 = (kg0<<9)     + ((arow ^ (kg0&7))<<3);
  const int aDst1 = ((kg0+1)<<9) + ((arow ^ ((kg0+1)&7))<<3);

  const int r16 = lane & 15, g = lane >> 4;
  const int colb  = wave << 6;
  const f16* bS = Bg + ((size_t)(colb + r16) << 3);

  f32x4 acc[4][4] = {};

  struct A16 { f32x4 q0, q1, q2, q3; };
  auto loadA = [&](int T)->A16 {
    const float* p = aG + (T<<7);
    A16 r;
    r.q0 = *(const f32x4*)(p);
    r.q1 = *(const f32x4*)(p+4);
    r.q2 = *(const f32x4*)(p+8);
    r.q3 = *(const f32x4*)(p+12);
    return r;
  };
  auto putA = [&](const A16& a, int buf){
    f16x8 lo, hi;
    lo[0]=(f16)a.q0[0]; lo[1]=(f16)a.q0[1]; lo[2]=(f16)a.q0[2]; lo[3]=(f16)a.q0[3];
    lo[4]=(f16)a.q1[0]; lo[5]=(f16)a.q1[1]; lo[6]=(f16)a.q1[2]; lo[7]=(f16)a.q1[3];
    hi[0]=(f16)a.q2[0]; hi[1]=(f16)a.q2[1]; hi[2]=(f16)a.q2[2]; hi[3]=(f16)a.q2[3];
    hi[4]=(f16)a.q3[0]; hi[5]=(f16)a.q3[1]; hi[6]=(f16)a.q3[2]; hi[7]=(f16)a.q3[3];
    *(f16x8*)&At[buf][aDst0] = lo;
    *(f16x8*)&At[buf][aDst1] = hi;
  };

  // prologue: A(0) staged; A(1) in flight across the lgkm-only barrier
  A16 aHold;
  {
    A16 a0 = loadA(0);
    aHold  = loadA(1);
    putA(a0, 0);                    // counted vmcnt wait on a0 only
  }
  asm volatile("s_waitcnt lgkmcnt(0)" ::: "memory");
  __builtin_amdgcn_sched_barrier(0);
  __builtin_amdgcn_s_barrier();
  __builtin_amdgcn_sched_barrier(0);

  for (int T = 0; T < 8; ++T){
    const int cur = T & 1;
    if (T < 7) putA(aHold, cur^1);  // A(T+1) -> other buffer (prev readers
                                    // done: barrier at end of T-1)
    #pragma unroll
    for (int kk = 0; kk < 4; ++kk){
      const int kgl = (kk<<2) + g;              // local kgrp 0..15
      const int kgG = (T<<4) + kgl;             // global kgrp 0..127
      f16x8 bfr[4];
      #pragma unroll
      for (int n = 0; n < 4; ++n)
        bfr[n] = *(const f16x8*)(bS + ((size_t)kgG<<12) + (n<<7));
      f16x8 af[4];
      #pragma unroll
      for (int m = 0; m < 4; ++m)
        af[m] = *(const f16x8*)&At[cur][(kgl<<9) + ((((m<<4)+r16) ^ (kgl&7))<<3)];
      __builtin_amdgcn_s_setprio(1);
      #pragma unroll
      for (int m = 0; m < 4; ++m)
        #pragma unroll
        for (int n = 0; n < 4; ++n)
          acc[m][n] = __builtin_amdgcn_mfma_f32_16x16x32_f16(af[m], bfr[n], acc[m][n], 0, 0, 0);
      __builtin_amdgcn_s_setprio(0);
    }
    if (T < 6) aHold = loadA(T+2);  // newest vmem; stays in flight
    if (T < 7){
      asm volatile("s_waitcnt lgkmcnt(0)" ::: "memory");
      __builtin_amdgcn_sched_barrier(0);
      __builtin_amdgcn_s_barrier();
      __builtin_amdgcn_sched_barrier(0);
    }
  }

  // epilogue: e = tanh(acc + dp[col]); score_row += v[col]*e
  float dpv[4], vvv[4];
  #pragma unroll
  for (int n = 0; n < 4; ++n){
    int c = colb + (n<<4) + r16;
    dpv[n] = dp[(b<<9) + c];
    vvv[n] = vvg[c];
  }
  float sp[4][4];
  #pragma unroll
  for (int m = 0; m < 4; ++m)
    #pragma unroll
    for (int r = 0; r < 4; ++r) sp[m][r] = 0.f;
  #pragma unroll
  for (int m = 0; m < 4; ++m)
    #pragma unroll
    for (int n = 0; n < 4; ++n)
      #pragma unroll
      for (int r = 0; r < 4; ++r){
        float e = fast_tanh(acc[m][n][r] + dpv[n]);
        sp[m][r] += vvv[n]*e;
      }
  #pragma unroll
  for (int m = 0; m < 4; ++m)
    #pragma unroll
    for (int r = 0; r < 4; ++r){
      float x = sp[m][r];
      x += __shfl_xor(x, 1);
      x += __shfl_xor(x, 2);
      x += __shfl_xor(x, 4);
      x += __shfl_xor(x, 8);
      if (r16 == 0) atomicAdd(&s_sc[(m<<4) + (g<<2) + r], x);
    }
  __syncthreads();

  // p = mask ? exp(score - C) : 0 ; denom partial; overwrite s_sc with p
  const float C = vC[0];
  if (tid < 64){
    float s = s_sc[tid];
    int mk = mask[(b<<11) + s0 + tid];
    float p = mk ? __expf(s - C) : 0.0f;
    s_sc[tid] = p;
    pbuf[(b<<11) + s0 + tid] = p;
    float d = p;
    #pragma unroll
    for (int o = 32; o >= 1; o >>= 1) d += __shfl_xor(d, o);
    if (tid == 0) denom[(b<<5) + (blockIdx.x & 31)] = d;
  }
  __syncthreads();

  // context partial: part[blk][c] = sum_{s=0..63} p_s * enc[b][s0+s][c]
  {
    const float2* e2 = (const float2*)(enc + ((size_t)(b*S_ + s0) << 10)) + tid;
    float ax = 0.f, ay = 0.f;
    #pragma unroll 4
    for (int s = 0; s < 64; ++s){
      float w = s_sc[s];
      float2 x = e2[s*512];
      ax += w * x.x; ay += w * x.y;
    }
    float2* pp = (float2*)part + ((size_t)blockIdx.x << 9) + tid;
    *pp = make_float2(ax, ay);
  }
}

// ---- k2: combine: D = sum denom; ctx = sum part / D; attn = pbuf / D ----
__global__ __launch_bounds__(256) void combine_k(const float* __restrict__ part,
                                                 const float* __restrict__ denom,
                                                 const float* __restrict__ pbuf,
                                                 float* __restrict__ ctx,
                                                 float* __restrict__ attn){
  const int b = blockIdx.x, tid = threadIdx.x;
  float D = 0.f;
  #pragma unroll
  for (int c = 0; c < 32; ++c) D += denom[(b<<5) + c];
  D = fmaxf(D, 1e-37f);
  const float inv = 1.0f / D;

  f32x4 acc = {0.f,0.f,0.f,0.f};
  const f32x4* p4 = (const f32x4*)part;
  #pragma unroll
  for (int c = 0; c < 32; ++c)
    acc += p4[(((b<<5)+c)<<8) + tid];
  ((f32x4*)ctx)[(b<<8) + tid] = acc * inv;

  #pragma unroll
  for (int i = 0; i < 8; ++i){
    int s = tid + (i<<8);
    attn[(b<<11) + s] = pbuf[(b<<11) + s] * inv;
  }
}

extern "C" void kernel_launch(void* const* d_in, const int* in_sizes, int n_in,
                              void* d_out, int out_size, void* d_ws, size_t ws_size,
                              hipStream_t stream){
  (void)in_sizes; (void)n_in; (void)out_size;
  const size_t WS_NEED = 1712384u + 8388608u;   // ~9.63 MB
  if (ws_size < WS_NEED) return;

  const float* dec_h = (const float*)d_in[0];
  const float* enc   = (const float*)d_in[1];
  const int*   mask  = (const int*)d_in[2];
  const float* Wd    = (const float*)d_in[3];
  const float* We    = (const float*)d_in[4];
  const float* v     = (const float*)d_in[5];
  float* out  = (float*)d_out;
  float* ctx  = out;                       // [64][1024]
  float* attn = out + B_*2*H_;             // [64][2048]

  char* ws = (char*)d_ws;
  f16*   Bg     = (f16*)ws;
  float* dproj  = (float*)(ws + 1048576);
  float* vC     = (float*)(ws + 1179648);
  float* pbuf   = (float*)(ws + 1179904);
  float* denom  = (float*)(ws + 1704192);
  float* part   = (float*)(ws + 1712384);

  prep_k   <<<2177, 256, 0, stream>>>(We, Bg, dec_h, Wd, dproj, v, vC);
  fused_k  <<<2048, 512, 0, stream>>>(enc, Bg, dproj, v, vC, mask, pbuf, denom, part);
  combine_k<<<B_, 256, 0, stream>>>(part, denom, pbuf, ctx, attn);
}

// Round 19
// 288.309 us; speedup vs baseline: 1.1261x; 1.1261x over previous
//
#include <hip/hip_runtime.h>

typedef _Float16 f16;
typedef f16  f16x4 __attribute__((ext_vector_type(4)));
typedef f16  f16x8 __attribute__((ext_vector_type(8)));
typedef float f32x4 __attribute__((ext_vector_type(4)));

#define B_  64
#define S_  2048
#define H_  512
#define K_  1024   // 2H

__device__ __forceinline__ float fast_tanh(float x){
  float ax = fabsf(x);
  float t  = __expf(-2.0f*ax);
  float r  = (1.0f - t) / (1.0f + t);
  return x < 0.0f ? -r : r;
}

// ---- k0: fused {We repack} + {dec_proj GEMV} + {C = sum|v|} ---------------
__global__ __launch_bounds__(256) void prep_k(const float* __restrict__ We,
                                              f16* __restrict__ Bg,
                                              const float* __restrict__ dh,
                                              const float* __restrict__ Wd,
                                              float* __restrict__ dp,
                                              const float* __restrict__ vvg,
                                              float* __restrict__ vC){
  __shared__ float s_dh[512];
  if (blockIdx.x < 2048){
    int idx = blockIdx.x*256 + threadIdx.x;      // 0..524287
    int k = idx >> 9, col = idx & 511;
    Bg[((k>>3)<<12) + (col<<3) + (k&7)] = (f16)We[idx];
  } else if (blockIdx.x < 2176){
    int idx = blockIdx.x - 2048;                 // 0..127
    int b = idx >> 1, cg = idx & 1;
    int col = (cg<<8) + threadIdx.x;
    for (int i = threadIdx.x; i < 512; i += 256) s_dh[i] = dh[(b<<9) + i];
    __syncthreads();
    float a0=0.f,a1=0.f,a2=0.f,a3=0.f;
    for (int k = 0; k < 512; k += 4){
      a0 += s_dh[k+0]*Wd[(k+0)*512 + col];
      a1 += s_dh[k+1]*Wd[(k+1)*512 + col];
      a2 += s_dh[k+2]*Wd[(k+2)*512 + col];
      a3 += s_dh[k+3]*Wd[(k+3)*512 + col];
    }
    dp[(b<<9) + col] = (a0+a1)+(a2+a3);
  } else {
    int t = threadIdx.x;
    float a = fabsf(vvg[t]) + fabsf(vvg[t+256]);
    #pragma unroll
    for (int o = 32; o >= 1; o >>= 1) a += __shfl_xor(a, o);
    if ((t & 63) == 0) s_dh[t>>6] = a;
    __syncthreads();
    if (t == 0) vC[0] = s_dh[0]+s_dh[1]+s_dh[2]+s_dh[3];
  }
}

// ---- k1: fused scores + unnorm-softmax + ctx partials ----
// R17 (best-known, 287.7 us total): B fragments read REGISTER-DIRECT from
// L2 (Bg is 1 MB, cache-resident; don't LDS-stage cache-fit data). No Bt,
// no B gload_lds, no vmem in the loop barrier. A (HBM-streamed, shared by
// all waves) keeps LDS dbuf + depth-2 register prefetch; barrier is
// lgkm-only so A(t+2) stays in flight across it.
__global__ __launch_bounds__(512, 2) void fused_k(
    const float* __restrict__ enc,   // [64][2048][1024] f32
    const f16*   __restrict__ Bg,    // [128][512][8] f16
    const float* __restrict__ dp,    // [64][512]
    const float* __restrict__ vvg,   // [512]
    const float* __restrict__ vC,    // [1]
    const int*   __restrict__ mask,  // [64][2048]
    float*       __restrict__ pbuf,  // [64][2048]
    float*       __restrict__ denom, // [64][32]
    float*       __restrict__ part)  // [2048][1024]
{
  __shared__ __align__(16) f16 At[2][2048];    // [kgrp4][row64^(kgrp<<1)][8]
  __shared__ float s_sc[64];

  const int tid  = threadIdx.x;
  const int lane = tid & 63;
  const int wave = tid >> 6;
  const int b    = blockIdx.x >> 5;
  const int s0   = (blockIdx.x & 31) << 6;

  if (tid < 64) s_sc[tid] = 0.0f;

  // A staging map (R8-proven): 8 threads/row, 4 f32 -> f16 each, XOR swizzle
  const int arow = tid >> 3;
  const int akq  = tid & 7;
  const int kgrp = akq >> 1, apar = akq & 1;
  const float* aG = enc + ((size_t)(b*S_ + s0 + arow) << 10) + (akq << 2);
  const int aDst = (kgrp<<9) + ((arow ^ (kgrp<<1))<<3) + (apar<<2);

  const int r16 = lane & 15, g = lane >> 4;
  const int aFrag = (g<<9) + ((r16 ^ (g<<1))<<3);
  const int colb  = wave << 6;

  // B fragment base: lane's 16B slice; step t at offset t*16384 halves
  const f16* bP = Bg + (g<<12) + ((colb + r16)<<3);

  f32x4 acc[4][4] = {};

  auto loadA = [&](int t)->f32x4 { return *(const f32x4*)(aG + (t<<5)); };
  auto putA  = [&](f32x4 a4, int buf){
    f16x4 h4; h4[0]=(f16)a4[0]; h4[1]=(f16)a4[1]; h4[2]=(f16)a4[2]; h4[3]=(f16)a4[3];
    *(f16x4*)&At[buf][aDst] = h4;
  };

  // prologue: A(0) staged; A(1) in flight; barrier = lgkm only
  {
    f32x4 a0 = loadA(0);
    putA(a0, 0);                     // waits a0
  }
  f32x4 aCur = loadA(1);
  asm volatile("s_waitcnt lgkmcnt(0)" ::: "memory");
  __builtin_amdgcn_sched_barrier(0);
  __builtin_amdgcn_s_barrier();
  __builtin_amdgcn_sched_barrier(0);

  for (int t = 0; t < 32; ++t){
    const int cur = t & 1;
    f32x4 aNext;
    if (t < 31){
      putA(aCur, cur^1);             // waits aCur (oldest outstanding vmem)
    }
    // B(t) fragments: register-direct from L2 (issued before the A prefetch
    // so the MFMA wait on them does NOT drain the newer A load)
    f16x8 bfr[4];
    #pragma unroll
    for (int n = 0; n < 4; ++n)
      bfr[n] = *(const f16x8*)(bP + (n<<7));
    if (t < 31){
      aNext = loadA(t+2 <= 31 ? t+2 : 31);   // newest; stays in flight
    }
    // A fragments from LDS + MFMA cluster
    __builtin_amdgcn_s_setprio(1);
    #pragma unroll
    for (int m = 0; m < 4; ++m){
      f16x8 af = *(const f16x8*)&At[cur][aFrag + (m<<7)];
      #pragma unroll
      for (int n = 0; n < 4; ++n)
        acc[m][n] = __builtin_amdgcn_mfma_f32_16x16x32_f16(af, bfr[n], acc[m][n], 0, 0, 0);
    }
    __builtin_amdgcn_s_setprio(0);
    if (t < 31){
      // A-visibility barrier only: no vmem drain (A(t+2) stays in flight)
      asm volatile("s_waitcnt lgkmcnt(0)" ::: "memory");
      __builtin_amdgcn_sched_barrier(0);
      __builtin_amdgcn_s_barrier();
      __builtin_amdgcn_sched_barrier(0);
      aCur = aNext;
    }
    bP += (1<<14);                   // advance to next K-step's B panel
  }

  // epilogue: e = tanh(acc + dp[col]); score_row += v[col]*e
  float dpv[4], vvv[4];
  #pragma unroll
  for (int n = 0; n < 4; ++n){
    int c = colb + (n<<4) + r16;
    dpv[n] = dp[(b<<9) + c];
    vvv[n] = vvg[c];
  }
  float sp[4][4];
  #pragma unroll
  for (int m = 0; m < 4; ++m)
    #pragma unroll
    for (int r = 0; r < 4; ++r) sp[m][r] = 0.f;
  #pragma unroll
  for (int m = 0; m < 4; ++m)
    #pragma unroll
    for (int n = 0; n < 4; ++n)
      #pragma unroll
      for (int r = 0; r < 4; ++r){
        float e = fast_tanh(acc[m][n][r] + dpv[n]);
        sp[m][r] += vvv[n]*e;
      }
  #pragma unroll
  for (int m = 0; m < 4; ++m)
    #pragma unroll
    for (int r = 0; r < 4; ++r){
      float x = sp[m][r];
      x += __shfl_xor(x, 1);
      x += __shfl_xor(x, 2);
      x += __shfl_xor(x, 4);
      x += __shfl_xor(x, 8);
      if (r16 == 0) atomicAdd(&s_sc[(m<<4) + (g<<2) + r], x);
    }
  __syncthreads();

  // p = mask ? exp(score - C) : 0 ; denom partial; overwrite s_sc with p
  const float C = vC[0];
  if (tid < 64){
    float s = s_sc[tid];
    int mk = mask[(b<<11) + s0 + tid];
    float p = mk ? __expf(s - C) : 0.0f;
    s_sc[tid] = p;
    pbuf[(b<<11) + s0 + tid] = p;
    float d = p;
    #pragma unroll
    for (int o = 32; o >= 1; o >>= 1) d += __shfl_xor(d, o);
    if (tid == 0) denom[(b<<5) + (blockIdx.x & 31)] = d;
  }
  __syncthreads();

  // context partial: part[blk][c] = sum_{s=0..63} p_s * enc[b][s0+s][c]
  {
    const float2* e2 = (const float2*)(enc + ((size_t)(b*S_ + s0) << 10)) + tid;
    float ax = 0.f, ay = 0.f;
    #pragma unroll 4
    for (int s = 0; s < 64; ++s){
      float w = s_sc[s];
      float2 x = e2[s*512];
      ax += w * x.x; ay += w * x.y;
    }
    float2* pp = (float2*)part + ((size_t)blockIdx.x << 9) + tid;
    *pp = make_float2(ax, ay);
  }
}

// ---- k2: combine: D = sum denom; ctx = sum part / D; attn = pbuf / D ----
__global__ __launch_bounds__(256) void combine_k(const float* __restrict__ part,
                                                 const float* __restrict__ denom,
                                                 const float* __restrict__ pbuf,
                                                 float* __restrict__ ctx,
                                                 float* __restrict__ attn){
  const int b = blockIdx.x, tid = threadIdx.x;
  float D = 0.f;
  #pragma unroll
  for (int c = 0; c < 32; ++c) D += denom[(b<<5) + c];
  D = fmaxf(D, 1e-37f);
  const float inv = 1.0f / D;

  f32x4 acc = {0.f,0.f,0.f,0.f};
  const f32x4* p4 = (const f32x4*)part;
  #pragma unroll
  for (int c = 0; c < 32; ++c)
    acc += p4[(((b<<5)+c)<<8) + tid];
  ((f32x4*)ctx)[(b<<8) + tid] = acc * inv;

  #pragma unroll
  for (int i = 0; i < 8; ++i){
    int s = tid + (i<<8);
    attn[(b<<11) + s] = pbuf[(b<<11) + s] * inv;
  }
}

extern "C" void kernel_launch(void* const* d_in, const int* in_sizes, int n_in,
                              void* d_out, int out_size, void* d_ws, size_t ws_size,
                              hipStream_t stream){
  (void)in_sizes; (void)n_in; (void)out_size;
  const size_t WS_NEED = 1712384u + 8388608u;   // ~9.63 MB
  if (ws_size < WS_NEED) return;

  const float* dec_h = (const float*)d_in[0];
  const float* enc   = (const float*)d_in[1];
  const int*   mask  = (const int*)d_in[2];
  const float* Wd    = (const float*)d_in[3];
  const float* We    = (const float*)d_in[4];
  const float* v     = (const float*)d_in[5];
  float* out  = (float*)d_out;
  float* ctx  = out;                       // [64][1024]
  float* attn = out + B_*2*H_;             // [64][2048]

  char* ws = (char*)d_ws;
  f16*   Bg     = (f16*)ws;
  float* dproj  = (float*)(ws + 1048576);
  float* vC     = (float*)(ws + 1179648);
  float* pbuf   = (float*)(ws + 1179904);
  float* denom  = (float*)(ws + 1704192);
  float* part   = (float*)(ws + 1712384);

  prep_k   <<<2177, 256, 0, stream>>>(We, Bg, dec_h, Wd, dproj, v, vC);
  fused_k  <<<2048, 512, 0, stream>>>(enc, Bg, dproj, v, vC, mask, pbuf, denom, part);
  combine_k<<<B_, 256, 0, stream>>>(part, denom, pbuf, ctx, attn);
}